// Round 4
// baseline (64.457 us; speedup 1.0000x reference)
//
#include <hip/hip_runtime.h>
#include <hip/hip_bf16.h>
#include <cstdint>

#define SS   2048
#define DD   128
#define KBLK 64
#define NKT  32                      // key tiles per batch
#define TILE_BYTES 16384             // 64x128 bf16 (K) or 128x64 bf16 (Vt)
#define NBLK 640

#define WS_K   ((size_t)0)
#define WS_V   ((size_t)16 * NKT * TILE_BYTES)            // 8 MB
#define WS_PO  ((size_t)16 * NKT * TILE_BYTES * 2)        // 16 MB
#define WS_ML  (WS_PO + (size_t)NBLK * 128 * 128 * 2)     // +20 MB
#define WS_NEED (WS_ML + (size_t)NBLK * 128 * 4)          // ~36.4 MB

typedef __attribute__((ext_vector_type(8)))  short short8;   // 8 bf16 (MFMA A/B)
typedef __attribute__((ext_vector_type(16))) float f32x16;   // 32x32 MFMA C/D
typedef __attribute__((ext_vector_type(4)))  float f32x4;

__device__ __forceinline__ unsigned short f2bf(float x) {
  return __builtin_bit_cast(unsigned short, (__bf16)x);
}
__device__ __forceinline__ float bfbits2f(unsigned int lo16shifted) {
  return __builtin_bit_cast(float, lo16shifted);
}

// ---- chunk schedule tables (QBLK=128, KBLK=64, CHUNK=8 tiles) ----
// q-block i has 2i+2 key tiles. Full 8-tile chunks first (448 blocks), then
// remainder chunks (192 blocks). blockIdx & 15 = batch (XCD pin).
__device__ __constant__ unsigned char FULLI[28]   = {3,4,5,6,7,7,8,8,9,9,10,10,11,11,11,12,12,12,13,13,13,14,14,14,15,15,15,15};
__device__ __constant__ unsigned char FULLBASE[16]= {0,0,0,0,1,2,3,4,6,8,10,12,15,18,21,24};
__device__ __constant__ unsigned char FULLCNT[16] = {0,0,0,1,1,1,1,2,2,2,2,3,3,3,3,4};
__device__ __constant__ signed   char SMALLIDX[16]= {0,1,2,-1,3,4,5,-1,6,7,8,-1,9,10,11,-1};
__device__ __constant__ unsigned char SMALLI[12]  = {0,1,2,4,5,6,8,9,10,12,13,14};
__device__ __constant__ unsigned char SMALLC[12]  = {0,0,0,1,1,1,2,2,2,3,3,3};
__device__ __constant__ unsigned char SMALLN[12]  = {2,4,6,2,4,6,2,4,6,2,4,6};

// ---------------------------------------------------------------------------
// Pre-pass: K -> bf16 row-major swizzled tiles; V -> transposed pi-permuted
// swizzled tiles Vt[d][slot].  pi(slot: s'=slot>>4, h=(slot>>3)&1, j=slot&7)
//   = 32*(s'>>1) + 16*(s'&1) + 8*(j>>2) + (j&3) + 4*h
// so the PV B-fragment is exactly the lane's own QK^T output registers.
// ---------------------------------------------------------------------------
__global__ __launch_bounds__(256) void prepack_kv4(
    const float* __restrict__ K, const float* __restrict__ V, char* __restrict__ ws)
{
  __shared__ float vf[64][129];
  const int b = blockIdx.x, t = blockIdx.y;
  const int tid = threadIdx.x;
  const float* Kt = K + ((size_t)b * SS + t * KBLK) * DD;
  const float* Vt = V + ((size_t)b * SS + t * KBLK) * DD;
  char* Kd = ws + WS_K + ((size_t)(b * NKT + t)) * TILE_BYTES;
  char* Vd = ws + WS_V + ((size_t)(b * NKT + t)) * TILE_BYTES;

  // K: row-major bf16 [64 keys][128 d], byteoff ^= (key&7)<<4
  #pragma unroll
  for (int u = 0; u < 4; ++u) {
    int row = u * 16 + (tid >> 4);
    int col = 8 * (tid & 15);
    const float4* sp = reinterpret_cast<const float4*>(Kt + (size_t)row * DD + col);
    float4 x = sp[0], y = sp[1];
    short8 w;
    w[0] = f2bf(x.x); w[1] = f2bf(x.y); w[2] = f2bf(x.z); w[3] = f2bf(x.w);
    w[4] = f2bf(y.x); w[5] = f2bf(y.y); w[6] = f2bf(y.z); w[7] = f2bf(y.w);
    int off = (row * 256 + col * 2) ^ ((row & 7) << 4);
    *reinterpret_cast<short8*>(Kd + off) = w;
  }
  // V: stage f32 tile to LDS (padded)
  #pragma unroll
  for (int u = 0; u < 4; ++u) {
    int row = u * 16 + (tid >> 4);
    int col = 8 * (tid & 15);
    const float4* sp = reinterpret_cast<const float4*>(Vt + (size_t)row * DD + col);
    float4 x = sp[0], y = sp[1];
    vf[row][col+0]=x.x; vf[row][col+1]=x.y; vf[row][col+2]=x.z; vf[row][col+3]=x.w;
    vf[row][col+4]=y.x; vf[row][col+5]=y.y; vf[row][col+6]=y.z; vf[row][col+7]=y.w;
  }
  __syncthreads();
  // Vt[d][pi(slot)] bf16 [128 d rows][64 slots], byteoff ^= (d&7)<<4
  #pragma unroll
  for (int q = 0; q < 4; ++q) {
    int idx = q * 256 + tid;          // 1024 chunks of 16B (8 slots)
    int d = idx >> 3, y8 = idx & 7;   // y8 = slot>>3 = s'*2 + h
    short8 w;
    #pragma unroll
    for (int j = 0; j < 8; ++j) {
      int a = ((y8 >> 2) << 5) | (((y8 >> 1) & 1) << 4) | ((j >> 2) << 3) | (j & 3) | ((y8 & 1) << 2);
      w[j] = f2bf(vf[a][d]);
    }
    int off = ((d << 7) + (y8 << 4)) ^ ((d & 7) << 4);
    *reinterpret_cast<short8*>(Vd + off) = w;
  }
}

__device__ __forceinline__ void stage_tile(const char* Ksrc, const char* Vsrc,
                                           char* Kl, char* Vl, int wid, int lane)
{
  #pragma unroll
  for (int i = 0; i < 4; ++i) {
    int off = wid * 4096 + i * 1024;
    __builtin_amdgcn_global_load_lds(
        (const __attribute__((address_space(1))) unsigned int*)(Ksrc + off + lane * 16),
        (__attribute__((address_space(3))) unsigned int*)(Kl + off), 16, 0, 0);
  }
  #pragma unroll
  for (int i = 0; i < 4; ++i) {
    int off = wid * 4096 + i * 1024;
    __builtin_amdgcn_global_load_lds(
        (const __attribute__((address_space(1))) unsigned int*)(Vsrc + off + lane * 16),
        (__attribute__((address_space(3))) unsigned int*)(Vl + off), 16, 0, 0);
  }
}

// ---------------------------------------------------------------------------
// Main: QBLK=128 (4 waves x 32 q-rows), 32x32x16 MFMA, no-max softmax,
// zero cross-lane ops in the K-loop. Every block writes a bf16 partial.
// ---------------------------------------------------------------------------
__global__ __launch_bounds__(256, 2) void sdpa_v4(
    const float* __restrict__ Q, const char* __restrict__ ws,
    unsigned short* __restrict__ partO, float* __restrict__ partML)
{
  __shared__ __align__(16) char smem[2 * 32768];

  const int y = blockIdx.x;
  int b, i, c, ntile;
  if (y < 448) { int k = y >> 4; b = y & 15; i = FULLI[k]; c = k - FULLBASE[i]; ntile = 8; }
  else         { int z = y - 448; int k = z >> 4; b = z & 15; i = SMALLI[k]; c = SMALLC[k]; ntile = SMALLN[k]; }

  const int tid  = threadIdx.x;
  const int lane = tid & 63;
  const int wid  = tid >> 6;
  const int l31  = lane & 31;
  const int h    = lane >> 5;

  const float* Qb  = Q + (size_t)b * SS * DD;
  const char*  Kws = ws + WS_K + ((size_t)(b * NKT + 8 * c)) * TILE_BYTES;
  const char*  Vws = ws + WS_V + ((size_t)(b * NKT + 8 * c)) * TILE_BYTES;

  // scale folded with log2(e): P = exp2(sacc)
  const float qscale = 0.08838834764831845f * 1.4426950408889634f;

  const int qg = 128 * i + wid * 32 + l31;   // this lane's q row (global)

  // ---- Q fragments: B-operand, 8 k-steps of 16 d each; slot k = h*8+j ----
  short8 qf[8];
  {
    const float* qrow = Qb + (size_t)qg * DD;
    #pragma unroll
    for (int s = 0; s < 8; ++s) {
      const float4* p = reinterpret_cast<const float4*>(qrow + s * 16 + h * 8);
      float4 x = p[0], z = p[1];
      short8 w;
      w[0] = f2bf(x.x * qscale); w[1] = f2bf(x.y * qscale);
      w[2] = f2bf(x.z * qscale); w[3] = f2bf(x.w * qscale);
      w[4] = f2bf(z.x * qscale); w[5] = f2bf(z.y * qscale);
      w[6] = f2bf(z.z * qscale); w[7] = f2bf(z.w * qscale);
      qf[s] = w;
    }
  }

  f32x16 o[4];
  #pragma unroll
  for (int dg = 0; dg < 4; ++dg)
    #pragma unroll
    for (int r = 0; r < 16; ++r) o[dg][r] = 0.f;
  float lsum = 0.f;

  int cur = 0;
  stage_tile(Kws, Vws, smem, smem + 16384, wid, lane);
  __syncthreads();

  for (int t = 0; t < ntile; ++t) {
    if (t + 1 < ntile) {
      char* nb = smem + (cur ^ 1) * 32768;
      stage_tile(Kws + (size_t)(t + 1) * TILE_BYTES, Vws + (size_t)(t + 1) * TILE_BYTES,
                 nb, nb + 16384, wid, lane);
    }
    const char* Kl = smem + cur * 32768;
    const char* Vl = Kl + 16384;
    const bool domask = (8 * c + t) >= 2 * i;   // last two diagonal tiles only

    short8 pf[4];
    float psum = 0.f;

    // ---- per key-group g (32 keys): S^T = K·Q^T, mask, exp2, pack ----
    #pragma unroll
    for (int g = 0; g < 2; ++g) {
      f32x16 acc;
      #pragma unroll
      for (int r = 0; r < 16; ++r) acc[r] = 0.f;
      const int key = g * 32 + l31;
      const int kbase = key * 256 + h * 16;
      const int kswz = (key & 7) << 4;
      __builtin_amdgcn_s_setprio(1);
      #pragma unroll
      for (int s = 0; s < 8; ++s) {
        short8 kf = *reinterpret_cast<const short8*>(Kl + ((kbase + s * 32) ^ kswz));
        acc = __builtin_amdgcn_mfma_f32_32x32x16_bf16(kf, qf[s], acc, 0, 0, 0);
      }
      __builtin_amdgcn_s_setprio(0);

      if (domask) {
        const int kb = (8 * c + t) * 64 + g * 32 + 4 * h;
        #pragma unroll
        for (int r = 0; r < 16; ++r) {
          int keyg = kb + (r & 3) + 8 * (r >> 2);
          if (keyg > qg) acc[r] = -1e30f;
        }
      }

      float pg[16];
      #pragma unroll
      for (int r = 0; r < 16; ++r) pg[r] = exp2f(acc[r]);
      float s0 = ((pg[0]+pg[1])+(pg[2]+pg[3])) + ((pg[4]+pg[5])+(pg[6]+pg[7]));
      float s1 = ((pg[8]+pg[9])+(pg[10]+pg[11])) + ((pg[12]+pg[13])+(pg[14]+pg[15]));
      psum += s0 + s1;

      short8 w0, w1;
      #pragma unroll
      for (int j = 0; j < 8; ++j) { w0[j] = f2bf(pg[j]); w1[j] = f2bf(pg[8 + j]); }
      pf[2 * g]     = w0;
      pf[2 * g + 1] = w1;
    }
    lsum += psum;

    // ---- PV: O^T[d][q] += Vt·P  (A-frag slots match pi permutation) ----
    __builtin_amdgcn_s_setprio(1);
    #pragma unroll
    for (int dg = 0; dg < 4; ++dg) {
      const int d = dg * 32 + l31;
      const int vbase = d * 128 + h * 16;
      const int vswz = (d & 7) << 4;
      #pragma unroll
      for (int s4 = 0; s4 < 4; ++s4) {
        short8 vf8 = *reinterpret_cast<const short8*>(Vl + ((vbase + s4 * 32) ^ vswz));
        o[dg] = __builtin_amdgcn_mfma_f32_32x32x16_bf16(vf8, pf[s4], o[dg], 0, 0, 0);
      }
    }
    __builtin_amdgcn_s_setprio(0);

    if (t + 1 < ntile) {
      __syncthreads();
      cur ^= 1;
    }
  }

  // ---- epilogue: one cross-lane reduce, store bf16 partial ----
  lsum += __shfl_xor(lsum, 32);

  unsigned short* po = partO + (size_t)y * (128 * 128) + (size_t)(wid * 32 + l31) * 128;
  #pragma unroll
  for (int dg = 0; dg < 4; ++dg)
    #pragma unroll
    for (int rq = 0; rq < 4; ++rq) {
      int d0 = dg * 32 + 8 * rq + 4 * h;
      ushort4 u;
      u.x = f2bf(o[dg][4 * rq + 0]);
      u.y = f2bf(o[dg][4 * rq + 1]);
      u.z = f2bf(o[dg][4 * rq + 2]);
      u.w = f2bf(o[dg][4 * rq + 3]);
      *reinterpret_cast<ushort4*>(po + d0) = u;
    }
  if (h == 0) partML[y * 128 + wid * 32 + l31] = lsum;
}

// ---------------------------------------------------------------------------
// Merge: O[b][128i+r][:] = (sum_c U_c) / (sum_c l_c)
// ---------------------------------------------------------------------------
__global__ __launch_bounds__(256) void merge_v4(
    const unsigned short* __restrict__ partO, const float* __restrict__ partML,
    float* __restrict__ O)
{
  const int b = blockIdx.x & 15, i = blockIdx.x >> 4;
  const int tid = threadIdx.x;
  const int r = tid >> 1, c0 = (tid & 1) * 64;

  float acc[64];
  #pragma unroll
  for (int u = 0; u < 64; ++u) acc[u] = 0.f;
  float ltot = 0.f;

  const int nf = FULLCNT[i];
  const int si = SMALLIDX[i];
  const int nch = nf + (si >= 0 ? 1 : 0);

  for (int c = 0; c < nch; ++c) {
    int slot = (c < nf) ? ((FULLBASE[i] + c) * 16 + b) : (448 + si * 16 + b);
    ltot += partML[slot * 128 + r];
    const uint4* po = reinterpret_cast<const uint4*>(
        partO + (size_t)slot * (128 * 128) + (size_t)r * 128 + c0);
    #pragma unroll
    for (int u = 0; u < 8; ++u) {
      uint4 v = po[u];
      acc[u*8+0] += bfbits2f(v.x << 16); acc[u*8+1] += bfbits2f(v.x & 0xffff0000u);
      acc[u*8+2] += bfbits2f(v.y << 16); acc[u*8+3] += bfbits2f(v.y & 0xffff0000u);
      acc[u*8+4] += bfbits2f(v.z << 16); acc[u*8+5] += bfbits2f(v.z & 0xffff0000u);
      acc[u*8+6] += bfbits2f(v.w << 16); acc[u*8+7] += bfbits2f(v.w & 0xffff0000u);
    }
  }
  float inv = 1.0f / ltot;
  float* orow = O + ((size_t)b * SS + 128 * i + r) * DD + c0;
  #pragma unroll
  for (int u = 0; u < 16; ++u) {
    float4 w;
    w.x = acc[4*u+0] * inv; w.y = acc[4*u+1] * inv;
    w.z = acc[4*u+2] * inv; w.w = acc[4*u+3] * inv;
    reinterpret_cast<float4*>(orow)[u] = w;
  }
}

// ---------------------------------------------------------------------------
// Emergency fallback (round-1 kernel, no ws) if workspace too small
// ---------------------------------------------------------------------------
__device__ __forceinline__ int sigma_col(int a) {
  return (a & 35) | ((a & 12) << 1) | ((a & 16) >> 2);
}

__global__ __launch_bounds__(256) void sdpa_naive(
    const float* __restrict__ Q, const float* __restrict__ K,
    const float* __restrict__ V, float* __restrict__ O)
{
  __shared__ __align__(16) char smem[64 * 128 * 2 * 2];
  char* Klds  = smem;
  char* Vtlds = smem + 64 * 128 * 2;

  const int b   = blockIdx.x;
  const int qb  = (int)gridDim.y - 1 - (int)blockIdx.y;
  const int q0  = qb * 64;
  const int tid = threadIdx.x;
  const int lane = tid & 63;
  const int wid  = tid >> 6;
  const int l15  = lane & 15;
  const int hi   = lane >> 4;

  const float* Qb = Q + (size_t)b * SS * DD;
  const float* Kb = K + (size_t)b * SS * DD;
  const float* Vb = V + (size_t)b * SS * DD;
  float*       Ob = O + (size_t)b * SS * DD;
  const float scale = 0.08838834764831845f;

  short8 qf[4];
  {
    const float* qrow = Qb + (size_t)(q0 + wid * 16 + l15) * DD;
    #pragma unroll
    for (int cc = 0; cc < 4; ++cc) {
      const float4* p = reinterpret_cast<const float4*>(qrow + 32 * cc + 8 * hi);
      float4 x = p[0], yv = p[1];
      short8 w;
      w[0]=f2bf(x.x*scale); w[1]=f2bf(x.y*scale); w[2]=f2bf(x.z*scale); w[3]=f2bf(x.w*scale);
      w[4]=f2bf(yv.x*scale); w[5]=f2bf(yv.y*scale); w[6]=f2bf(yv.z*scale); w[7]=f2bf(yv.w*scale);
      qf[cc] = w;
    }
  }

  f32x4 o[8];
  #pragma unroll
  for (int nt = 0; nt < 8; ++nt) o[nt] = (f32x4){0.f,0.f,0.f,0.f};
  float m = -INFINITY, lsum = 0.f;

  const int ntile = qb + 1;
  for (int t = 0; t < ntile; ++t) {
    const int kv0 = t * 64;
    if (t) __syncthreads();
    #pragma unroll
    for (int u = 0; u < 4; ++u) {
      int row = u * 16 + (tid >> 4);
      int col = 8 * (tid & 15);
      const float4* sp = reinterpret_cast<const float4*>(Kb + (size_t)(kv0 + row) * DD + col);
      float4 x = sp[0], yv = sp[1];
      short8 w;
      w[0]=f2bf(x.x); w[1]=f2bf(x.y); w[2]=f2bf(x.z); w[3]=f2bf(x.w);
      w[4]=f2bf(yv.x); w[5]=f2bf(yv.y); w[6]=f2bf(yv.z); w[7]=f2bf(yv.w);
      int off = (row * 256 + col * 2) ^ ((row & 7) << 4);
      *reinterpret_cast<short8*>(Klds + off) = w;
    }
    #pragma unroll
    for (int u = 0; u < 4; ++u) {
      int row = u * 16 + (tid >> 4);
      int col = 8 * (tid & 15);
      const float4* sp = reinterpret_cast<const float4*>(Vb + (size_t)(kv0 + row) * DD + col);
      float4 x = sp[0], yv = sp[1];
      int sc = sigma_col(row);
      float vals[8] = {x.x, x.y, x.z, x.w, yv.x, yv.y, yv.z, yv.w};
      #pragma unroll
      for (int j = 0; j < 8; ++j) {
        int d = col + j;
        int off = ((d << 7) + (sc << 1)) ^ ((((d >> 3) ^ d) & 7) << 4);
        *reinterpret_cast<unsigned short*>(Vtlds + off) = f2bf(vals[j]);
      }
    }
    __syncthreads();

    f32x4 sacc[4];
    #pragma unroll
    for (int g = 0; g < 4; ++g) {
      f32x4 acc = {0.f,0.f,0.f,0.f};
      #pragma unroll
      for (int cc = 0; cc < 4; ++cc) {
        int row = g * 16 + l15;
        int off = (row * 256 + (32 * cc + 8 * hi) * 2) ^ ((row & 7) << 4);
        short8 kf = *reinterpret_cast<const short8*>(Klds + off);
        acc = __builtin_amdgcn_mfma_f32_16x16x32_bf16(kf, qf[cc], acc, 0, 0, 0);
      }
      sacc[g] = acc;
    }
    if (t == ntile - 1) {
      const int q = q0 + wid * 16 + l15;
      #pragma unroll
      for (int g = 0; g < 4; ++g)
        #pragma unroll
        for (int ii = 0; ii < 4; ++ii) {
          int key = kv0 + g * 16 + 4 * hi + ii;
          if (key > q) sacc[g][ii] = -1e30f;
        }
    }
    float tmax = -INFINITY;
    #pragma unroll
    for (int g = 0; g < 4; ++g)
      #pragma unroll
      for (int ii = 0; ii < 4; ++ii) tmax = fmaxf(tmax, sacc[g][ii]);
    tmax = fmaxf(tmax, __shfl_xor(tmax, 16));
    tmax = fmaxf(tmax, __shfl_xor(tmax, 32));
    float mnew = fmaxf(m, tmax);
    float corr = __expf(m - mnew);
    m = mnew;
    float p[4][4]; float psum = 0.f;
    #pragma unroll
    for (int g = 0; g < 4; ++g)
      #pragma unroll
      for (int ii = 0; ii < 4; ++ii) {
        float pv = __expf(sacc[g][ii] - mnew);
        p[g][ii] = pv; psum += pv;
      }
    psum += __shfl_xor(psum, 16);
    psum += __shfl_xor(psum, 32);
    lsum = lsum * corr + psum;
    float corrO[4];
    #pragma unroll
    for (int ii = 0; ii < 4; ++ii) corrO[ii] = __shfl(corr, 4 * hi + ii);
    #pragma unroll
    for (int nt = 0; nt < 8; ++nt)
      #pragma unroll
      for (int ii = 0; ii < 4; ++ii) o[nt][ii] *= corrO[ii];
    short8 pfr[2];
    #pragma unroll
    for (int ks = 0; ks < 2; ++ks) {
      short8 w;
      #pragma unroll
      for (int ii = 0; ii < 4; ++ii) { w[ii] = f2bf(p[2*ks][ii]); w[4+ii] = f2bf(p[2*ks+1][ii]); }
      pfr[ks] = w;
    }
    #pragma unroll
    for (int ks = 0; ks < 2; ++ks)
      #pragma unroll
      for (int nt = 0; nt < 8; ++nt) {
        int d = nt * 16 + l15;
        int off = ((d << 7) + (ks * 32 + 8 * hi) * 2) ^ ((((d >> 3) ^ d) & 7) << 4);
        short8 vvf = *reinterpret_cast<const short8*>(Vtlds + off);
        o[nt] = __builtin_amdgcn_mfma_f32_16x16x32_bf16(pfr[ks], vvf, o[nt], 0, 0, 0);
      }
  }
  float rl = 1.0f / lsum;
  float rlO[4];
  #pragma unroll
  for (int ii = 0; ii < 4; ++ii) rlO[ii] = __shfl(rl, 4 * hi + ii);
  const int qrow = q0 + wid * 16;
  #pragma unroll
  for (int nt = 0; nt < 8; ++nt)
    #pragma unroll
    for (int ii = 0; ii < 4; ++ii)
      Ob[(size_t)(qrow + 4 * hi + ii) * DD + nt * 16 + l15] = o[nt][ii] * rlO[ii];
}

extern "C" void kernel_launch(void* const* d_in, const int* in_sizes, int n_in,
                              void* d_out, int out_size, void* d_ws, size_t ws_size,
                              hipStream_t stream) {
  const float* Q = (const float*)d_in[0];
  const float* K = (const float*)d_in[1];
  const float* V = (const float*)d_in[2];
  float* O = (float*)d_out;
  char* ws = (char*)d_ws;

  if (ws_size >= WS_NEED) {
    unsigned short* partO = (unsigned short*)(ws + WS_PO);
    float* partML = (float*)(ws + WS_ML);
    prepack_kv4<<<dim3(16, NKT), 256, 0, stream>>>(K, V, ws);
    sdpa_v4<<<dim3(NBLK), 256, 0, stream>>>(Q, ws, partO, partML);
    merge_v4<<<dim3(256), 256, 0, stream>>>(partO, partML, O);
  } else {
    sdpa_naive<<<dim3(16, 32), 256, 0, stream>>>(Q, K, V, O);
  }
}